// Round 7
// baseline (277.308 us; speedup 1.0000x reference)
//
#include <hip/hip_runtime.h>

// Sigmoid-attention: O = sigmoid(Q K^T / 8) V per (b,h). B*H=64, S=2048, D=64.
// R11: occupancy via GRID, with natural register allocation. R10 (LDS-free)
// proved staging was never the limiter (97us ~= R6's 96.5 with identical pipe
// util) AND compiled to VGPR=52 <= 64 — the 8-waves/SIMD budget. Limiter is
// the grid: 1024 blocks = 4 blocks/CU = 16 waves/CU. R11: QPW=16, QPB=64 ->
// 2048 blocks = 8 blocks/CU = 32 waves/CU, PROVIDED natural VGPR stays <=64.
// No launch_bounds forcing (R8/R9 showed (..,8) coerces 32 regs + spills).
// Per-wave work halves (8 MFMA + 16 trans/iter); 2x waves interleave the
// QK->sigmoid->PV dependency chains across the MFMA and trans pipes.

typedef __bf16 bf16_t;
typedef __attribute__((ext_vector_type(8))) __bf16 bf16x8;
typedef __attribute__((ext_vector_type(4))) float  f32x4;

#if defined(__HIP_DEVICE_COMPILE__) && __has_builtin(__builtin_amdgcn_exp2f)
#define FAST_EXP2(x) __builtin_amdgcn_exp2f(x)
#else
#define FAST_EXP2(x) exp2f(x)
#endif
#if defined(__HIP_DEVICE_COMPILE__) && __has_builtin(__builtin_amdgcn_rcpf)
#define FAST_RCP(x) __builtin_amdgcn_rcpf(x)
#else
#define FAST_RCP(x) (1.0f/(x))
#endif

static constexpr int SEQ = 2048;
static constexpr int DH  = 64;
static constexpr int KB  = 32;           // keys per chunk
static constexpr int NIT = SEQ / KB;     // 64 chunks
static constexpr int QPW = 16;           // q-rows per wave
static constexpr int QPB = 64;           // q-rows per block (4 waves x 16)
static constexpr int CHUNK = 4096;       // bf16 per (head,chunk) ws block (8 KB)

// ws image layout per (head,chunk) — identical to R5/R6:
//   [0,2048)   K frags: slot(f=ks*2+dh, lane, j) =
//              K[kb + ks*16 + (lane&15)][dh*32 + (lane>>4)*8 + j]
//   [2048,4096) V frags (kappa-permuted): slot(dt, lane, j) =
//              V[kb + kappa(lane>>4,j)][dt*16 + (lane&15)],
//              kappa(g4,j) = (j>>2)*16 + g4*4 + (j&3)

// ---------------- prepass (unchanged from R6, ~20us) ---------------------
__global__ __launch_bounds__(256)
void sigattn_prepass(const float* __restrict__ Kg, const float* __restrict__ Vg,
                     bf16_t* __restrict__ ws)
{
    const int bh = blockIdx.x, it = blockIdx.y;
    const int t  = threadIdx.x;
    const int kb = it * KB;
    const size_t hbase = (size_t)bh * SEQ * DH;
    bf16_t* wbase = ws + ((size_t)bh * NIT + it) * CHUNK;

    {
        const int f = t >> 6, lane = t & 63;
        const int ks = f >> 1, dh = f & 1, c16 = lane & 15, g4 = lane >> 4;
        const float* p = Kg + hbase + (size_t)(kb + ks * 16 + c16) * DH + dh * 32 + g4 * 8;
        f32x4 a = *(const f32x4*)p;
        f32x4 b = *(const f32x4*)(p + 4);
        bf16x8 o;
        o[0] = (bf16_t)a.x; o[1] = (bf16_t)a.y; o[2] = (bf16_t)a.z; o[3] = (bf16_t)a.w;
        o[4] = (bf16_t)b.x; o[5] = (bf16_t)b.y; o[6] = (bf16_t)b.z; o[7] = (bf16_t)b.w;
        *(bf16x8*)&wbase[(size_t)t * 8] = o;
    }
    {
        const int lane = t & 63, dt = t >> 6;
        const int c16 = lane & 15, g4 = lane >> 4;
        const float* p = Vg + hbase + (size_t)kb * DH + dt * 16 + c16;
        bf16x8 o;
        #pragma unroll
        for (int j = 0; j < 8; ++j) {
            const int row = (j >> 2) * 16 + g4 * 4 + (j & 3);   // kappa(g4, j)
            o[j] = (bf16_t)p[(size_t)row * DH];
        }
        *(bf16x8*)&wbase[2048 + (size_t)t * 8] = o;
    }
}

// ---------------- main kernel: LDS-free, QPW=16, 2048 blocks -------------
__global__ __launch_bounds__(256, 4)
void sigattn_main(const float* __restrict__ Qg, const bf16_t* __restrict__ ws,
                  float* __restrict__ Og)
{
    const int t    = threadIdx.x;
    const int wave = t >> 6;
    const int lane = t & 63;
    const int c16  = lane & 15;
    const int g4   = lane >> 4;

    const int bh    = blockIdx.x;
    const int qtile = blockIdx.y;

    const float* Qp = Qg + (size_t)bh * SEQ * DH;
    float*       Op = Og + (size_t)bh * SEQ * DH;
    const bf16_t* wsh = ws + (size_t)bh * NIT * CHUNK;

    const int qwave = qtile * QPB + wave * QPW;   // 16 q-rows per wave

    // Q fragments (pre-scaled by -log2(e)/8): B-frag layout, one 16-row strip
    const float qscale = -0.125f * 1.44269504088896340736f;
    bf16x8 qf[2];
    #pragma unroll
    for (int dh = 0; dh < 2; ++dh) {
        const float* p = Qp + (size_t)(qwave + c16) * DH + dh * 32 + g4 * 8;
        f32x4 a = *(const f32x4*)p;
        f32x4 b = *(const f32x4*)(p + 4);
        bf16x8 f;
        f[0] = (bf16_t)(a.x * qscale); f[1] = (bf16_t)(a.y * qscale);
        f[2] = (bf16_t)(a.z * qscale); f[3] = (bf16_t)(a.w * qscale);
        f[4] = (bf16_t)(b.x * qscale); f[5] = (bf16_t)(b.y * qscale);
        f[6] = (bf16_t)(b.z * qscale); f[7] = (bf16_t)(b.w * qscale);
        qf[dh] = f;
    }

    // per-lane base into the frag image: slot (f*64+lane) -> byte-linear
    const bf16_t* lbase = wsh + (size_t)lane * 8;

    f32x4 acc[4] = {};   // [dt], C-layout: row=q(g4*4+r), col=d(c16)

    // No LDS, no barriers: each wave streams the L2-resident frag image.
    // Unroll 2 so the scheduler hoists iteration i+1's loads over i's compute.
    #pragma unroll 2
    for (int it = 0; it < NIT; ++it) {
        const bf16_t* cb = lbase + (size_t)it * CHUNK;
        bf16x8 kf[4];
        #pragma unroll
        for (int f = 0; f < 4; ++f) kf[f] = *(const bf16x8*)&cb[(size_t)f * 64 * 8];

        // S^T = K*Q^T: lane holds keys {g4*4+r} (s0) and {16+g4*4+r} (s1), q=c16
        f32x4 s0 = {0.f, 0.f, 0.f, 0.f}, s1 = {0.f, 0.f, 0.f, 0.f};
        __builtin_amdgcn_s_setprio(1);
        s0 = __builtin_amdgcn_mfma_f32_16x16x32_bf16(kf[0], qf[0], s0, 0, 0, 0);
        s0 = __builtin_amdgcn_mfma_f32_16x16x32_bf16(kf[1], qf[1], s0, 0, 0, 0);
        s1 = __builtin_amdgcn_mfma_f32_16x16x32_bf16(kf[2], qf[0], s1, 0, 0, 0);
        s1 = __builtin_amdgcn_mfma_f32_16x16x32_bf16(kf[3], qf[1], s1, 0, 0, 0);
        __builtin_amdgcn_s_setprio(0);

        // V frag reads issued here: latency hides under the sigmoid
        bf16x8 vf[4];
        #pragma unroll
        for (int f = 0; f < 4; ++f) vf[f] = *(const bf16x8*)&cb[2048 + (size_t)f * 64 * 8];

        // sigmoid -> bf16x8 = A-frag of 16x16x32 PV; A k-slot g4*8+j holds
        // key kappa(g4,j), matching the ws V permutation.
        bf16x8 p8;
        #pragma unroll
        for (int r = 0; r < 4; ++r) p8[r]     = (bf16_t)FAST_RCP(1.0f + FAST_EXP2(s0[r]));
        #pragma unroll
        for (int r = 0; r < 4; ++r) p8[4 + r] = (bf16_t)FAST_RCP(1.0f + FAST_EXP2(s1[r]));

        __builtin_amdgcn_s_setprio(1);
        #pragma unroll
        for (int dt = 0; dt < 4; ++dt)
            acc[dt] = __builtin_amdgcn_mfma_f32_16x16x32_bf16(p8, vf[dt], acc[dt], 0, 0, 0);
        __builtin_amdgcn_s_setprio(0);
    }

    const int q0 = qwave + g4 * 4;
    #pragma unroll
    for (int r = 0; r < 4; ++r) {
        float* po = Op + (size_t)(q0 + r) * DH + c16;
        po[0]  = acc[0][r];
        po[16] = acc[1][r];
        po[32] = acc[2][r];
        po[48] = acc[3][r];
    }
}

// ---------------- fallback: R7 fused single kernel (no ws needed) --------
__global__ __launch_bounds__(256, 4)
void sigattn_fallback(const float* __restrict__ Qg, const float* __restrict__ Kg,
                      const float* __restrict__ Vg, float* __restrict__ Og)
{
    static constexpr int FQPB = 128;
    __shared__ __align__(16) bf16_t buf[2][2 * CHUNK];
    const int t = threadIdx.x, wave = t >> 6, lane = t & 63;
    const int c16 = lane & 15, g4 = lane >> 4;
    const int bh = blockIdx.x, qtile = blockIdx.y;
    const size_t hbase = (size_t)bh * SEQ * DH;
    const float* Qp = Qg + hbase; const float* Kp = Kg + hbase;
    const float* Vp = Vg + hbase; float* Op = Og + hbase;
    const int qwave = qtile * FQPB + wave * 32;
    const float qscale = -0.125f * 1.44269504088896340736f;
    bf16x8 qf[2][2];
    #pragma unroll
    for (int qs = 0; qs < 2; ++qs)
        #pragma unroll
        for (int dh = 0; dh < 2; ++dh) {
            const float* p = Qp + (size_t)(qwave + qs * 16 + c16) * DH + dh * 32 + g4 * 8;
            f32x4 a = *(const f32x4*)p; f32x4 b = *(const f32x4*)(p + 4);
            bf16x8 f;
            f[0]=(bf16_t)(a.x*qscale); f[1]=(bf16_t)(a.y*qscale); f[2]=(bf16_t)(a.z*qscale); f[3]=(bf16_t)(a.w*qscale);
            f[4]=(bf16_t)(b.x*qscale); f[5]=(bf16_t)(b.y*qscale); f[6]=(bf16_t)(b.z*qscale); f[7]=(bf16_t)(b.w*qscale);
            qf[qs][dh] = f;
        }
    f32x4 kst[2][2]; float vst[2][8];
    auto issue_loads2 = [&](int su) {
        #pragma unroll
        for (int c = 0; c < 2; ++c) {
            const int kb0 = (2 * su + c) * KB;
            const float* pk = Kp + (size_t)(kb0 + (wave >> 1) * 16 + c16) * DH + (wave & 1) * 32 + g4 * 8;
            kst[c][0] = *(const f32x4*)pk; kst[c][1] = *(const f32x4*)(pk + 4);
            const float* pv = Vp + (size_t)(kb0 + g4 * 4) * DH + wave * 16 + c16;
            #pragma unroll
            for (int h = 0; h < 2; ++h)
                #pragma unroll
                for (int j = 0; j < 4; ++j) vst[c][h * 4 + j] = pv[(size_t)(h * 16 + j) * DH];
        }
    };
    auto store2 = [&](int nb) {
        #pragma unroll
        for (int c = 0; c < 2; ++c) {
            bf16x8 k8;
            #pragma unroll
            for (int i = 0; i < 4; ++i) { k8[i] = (bf16_t)kst[c][0][i]; k8[4+i] = (bf16_t)kst[c][1][i]; }
            *(bf16x8*)&buf[nb][c * CHUNK + t * 8] = k8;
            bf16x8 v8;
            #pragma unroll
            for (int j = 0; j < 8; ++j) v8[j] = (bf16_t)vst[c][j];
            *(bf16x8*)&buf[nb][c * CHUNK + 2048 + t * 8] = v8;
        }
    };
    issue_loads2(0); store2(0);
    f32x4 acc[2][4] = {};
    for (int su = 0; su < NIT / 2; ++su) {
        const int cur = su & 1;
        __syncthreads();
        if (su + 1 < NIT / 2) issue_loads2(su + 1);
        #pragma unroll
        for (int h = 0; h < 2; ++h) {
            const bf16_t* base = &buf[cur][h * CHUNK];
            bf16x8 kf[4], vf[4];
            #pragma unroll
            for (int f = 0; f < 4; ++f) kf[f] = *(const bf16x8*)&base[(f * 64 + lane) * 8];
            #pragma unroll
            for (int f = 0; f < 4; ++f) vf[f] = *(const bf16x8*)&base[2048 + (f * 64 + lane) * 8];
            #pragma unroll
            for (int qs = 0; qs < 2; ++qs) {
                f32x4 s0 = {0.f,0.f,0.f,0.f}, s1 = {0.f,0.f,0.f,0.f};
                s0 = __builtin_amdgcn_mfma_f32_16x16x32_bf16(kf[0], qf[qs][0], s0, 0, 0, 0);
                s0 = __builtin_amdgcn_mfma_f32_16x16x32_bf16(kf[1], qf[qs][1], s0, 0, 0, 0);
                s1 = __builtin_amdgcn_mfma_f32_16x16x32_bf16(kf[2], qf[qs][0], s1, 0, 0, 0);
                s1 = __builtin_amdgcn_mfma_f32_16x16x32_bf16(kf[3], qf[qs][1], s1, 0, 0, 0);
                bf16x8 p8;
                #pragma unroll
                for (int r = 0; r < 4; ++r) p8[r]     = (bf16_t)FAST_RCP(1.0f + FAST_EXP2(s0[r]));
                #pragma unroll
                for (int r = 0; r < 4; ++r) p8[4 + r] = (bf16_t)FAST_RCP(1.0f + FAST_EXP2(s1[r]));
                #pragma unroll
                for (int dt = 0; dt < 4; ++dt)
                    acc[qs][dt] = __builtin_amdgcn_mfma_f32_16x16x32_bf16(p8, vf[dt], acc[qs][dt], 0, 0, 0);
            }
        }
        if (su + 1 < NIT / 2) store2(cur ^ 1);
    }
    #pragma unroll
    for (int qs = 0; qs < 2; ++qs) {
        const int q0 = qwave + qs * 16 + g4 * 4;
        #pragma unroll
        for (int r = 0; r < 4; ++r) {
            float* po = Op + (size_t)(q0 + r) * DH + c16;
            po[0]  = acc[qs][0][r];
            po[16] = acc[qs][1][r];
            po[32] = acc[qs][2][r];
            po[48] = acc[qs][3][r];
        }
    }
}

extern "C" void kernel_launch(void* const* d_in, const int* in_sizes, int n_in,
                              void* d_out, int out_size, void* d_ws, size_t ws_size,
                              hipStream_t stream)
{
    const float* q = (const float*)d_in[0];
    const float* k = (const float*)d_in[1];
    const float* v = (const float*)d_in[2];
    float* o = (float*)d_out;
    const size_t need = 64ull * NIT * CHUNK * sizeof(bf16_t);   // 32 MB
    if (ws_size >= need) {
        sigattn_prepass<<<dim3(64, NIT), dim3(256), 0, stream>>>(k, v, (bf16_t*)d_ws);
        // grid x = bh: XCD = (x + 64*y) % 8 = bh % 8 -> per-XCD ws working
        // set = 8 heads x 512KB = 4MB, L2-resident. 2048 blocks = 8/CU.
        sigattn_main<<<dim3(64, SEQ / QPB), dim3(256), 0, stream>>>(q, (const bf16_t*)d_ws, o);
    } else {
        sigattn_fallback<<<dim3(64, SEQ / 128), dim3(256), 0, stream>>>(q, k, v, o);
    }
}

// Round 8
// 217.904 us; speedup vs baseline: 1.2726x; 1.2726x over previous
//
#include <hip/hip_runtime.h>

// Sigmoid-attention: O = sigmoid(Q K^T / 8) V per (b,h). B*H=64, S=2048, D=64.
// R12: R9's structure with the ONE line fixed. Experiment matrix so far:
//  - QPW=32 (R6/R10): dependency-bound at 4 waves/SIMD -> 97us (LDS or not).
//  - QPW=16 no-LDS (R11): per-wave loads not amortized -> L2-bound, 169us.
//  - QPW=16 + LDS (R9): right structure, but launch_bounds(256,8) FORCED
//    VGPR=32 -> spills (WRITE 260MB) -> 259us.
// R12 = QPW=16 + LDS staging (global loads amortized 4x across block; 1GB L2
// traffic) + single-chunk dbuf (16KB LDS -> 10 blocks/CU LDS-wise) + grid
// 2048 (8 blocks/CU) + launch_bounds(256,4): allocator free to use <=128,
// natural pressure ~50 (R10=52, R11=36) -> <=64 -> HW co-schedules 8
// blocks/CU = 8 waves/SIMD. 2x wave parallelism interleaves the serial
// QK->sigmoid->PV chains across MFMA and trans pipes.

typedef __bf16 bf16_t;
typedef __attribute__((ext_vector_type(8))) __bf16 bf16x8;
typedef __attribute__((ext_vector_type(4))) float  f32x4;

#if defined(__HIP_DEVICE_COMPILE__) && __has_builtin(__builtin_amdgcn_exp2f)
#define FAST_EXP2(x) __builtin_amdgcn_exp2f(x)
#else
#define FAST_EXP2(x) exp2f(x)
#endif
#if defined(__HIP_DEVICE_COMPILE__) && __has_builtin(__builtin_amdgcn_rcpf)
#define FAST_RCP(x) __builtin_amdgcn_rcpf(x)
#else
#define FAST_RCP(x) (1.0f/(x))
#endif

static constexpr int SEQ = 2048;
static constexpr int DH  = 64;
static constexpr int KB  = 32;           // keys per chunk
static constexpr int NIT = SEQ / KB;     // 64 chunks
static constexpr int QPW = 16;           // q-rows per wave
static constexpr int QPB = 64;           // q-rows per block (4 waves x 16)
static constexpr int CHUNK = 4096;       // bf16 per (head,chunk) ws block (8 KB)

// ws image layout per (head,chunk) — identical to R5/R6:
//   [0,2048)   K frags: slot(f=ks*2+dh, lane, j) =
//              K[kb + ks*16 + (lane&15)][dh*32 + (lane>>4)*8 + j]
//   [2048,4096) V frags (kappa-permuted): slot(dt, lane, j) =
//              V[kb + kappa(lane>>4,j)][dt*16 + (lane&15)],
//              kappa(g4,j) = (j>>2)*16 + g4*4 + (j&3)

// ---------------- prepass (unchanged from R6, ~20us) ---------------------
__global__ __launch_bounds__(256)
void sigattn_prepass(const float* __restrict__ Kg, const float* __restrict__ Vg,
                     bf16_t* __restrict__ ws)
{
    const int bh = blockIdx.x, it = blockIdx.y;
    const int t  = threadIdx.x;
    const int kb = it * KB;
    const size_t hbase = (size_t)bh * SEQ * DH;
    bf16_t* wbase = ws + ((size_t)bh * NIT + it) * CHUNK;

    {
        const int f = t >> 6, lane = t & 63;
        const int ks = f >> 1, dh = f & 1, c16 = lane & 15, g4 = lane >> 4;
        const float* p = Kg + hbase + (size_t)(kb + ks * 16 + c16) * DH + dh * 32 + g4 * 8;
        f32x4 a = *(const f32x4*)p;
        f32x4 b = *(const f32x4*)(p + 4);
        bf16x8 o;
        o[0] = (bf16_t)a.x; o[1] = (bf16_t)a.y; o[2] = (bf16_t)a.z; o[3] = (bf16_t)a.w;
        o[4] = (bf16_t)b.x; o[5] = (bf16_t)b.y; o[6] = (bf16_t)b.z; o[7] = (bf16_t)b.w;
        *(bf16x8*)&wbase[(size_t)t * 8] = o;
    }
    {
        const int lane = t & 63, dt = t >> 6;
        const int c16 = lane & 15, g4 = lane >> 4;
        const float* p = Vg + hbase + (size_t)kb * DH + dt * 16 + c16;
        bf16x8 o;
        #pragma unroll
        for (int j = 0; j < 8; ++j) {
            const int row = (j >> 2) * 16 + g4 * 4 + (j & 3);   // kappa(g4, j)
            o[j] = (bf16_t)p[(size_t)row * DH];
        }
        *(bf16x8*)&wbase[2048 + (size_t)t * 8] = o;
    }
}

// ---------------- main: QPW=16, LDS dbuf, natural regs, 8 blocks/CU ------
__global__ __launch_bounds__(256, 4)
void sigattn_main(const float* __restrict__ Qg, const bf16_t* __restrict__ ws,
                  float* __restrict__ Og)
{
    // single-chunk double-buffer: 8KB x2 = 16KB
    __shared__ __align__(16) bf16_t buf[2][CHUNK];

    const int t    = threadIdx.x;
    const int wave = t >> 6;
    const int lane = t & 63;
    const int c16  = lane & 15;
    const int g4   = lane >> 4;

    const int bh    = blockIdx.x;
    const int qtile = blockIdx.y;

    const float* Qp = Qg + (size_t)bh * SEQ * DH;
    float*       Op = Og + (size_t)bh * SEQ * DH;
    const bf16_t* wsh = ws + (size_t)bh * NIT * CHUNK;

    const int qwave = qtile * QPB + wave * QPW;   // 16 q-rows per wave

    // Q fragments (pre-scaled by -log2(e)/8): B-frag layout, one 16-row strip
    const float qscale = -0.125f * 1.44269504088896340736f;
    bf16x8 qf[2];
    #pragma unroll
    for (int dh = 0; dh < 2; ++dh) {
        const float* p = Qp + (size_t)(qwave + c16) * DH + dh * 32 + g4 * 8;
        f32x4 a = *(const f32x4*)p;
        f32x4 b = *(const f32x4*)(p + 4);
        bf16x8 f;
        f[0] = (bf16_t)(a.x * qscale); f[1] = (bf16_t)(a.y * qscale);
        f[2] = (bf16_t)(a.z * qscale); f[3] = (bf16_t)(a.w * qscale);
        f[4] = (bf16_t)(b.x * qscale); f[5] = (bf16_t)(b.y * qscale);
        f[6] = (bf16_t)(b.z * qscale); f[7] = (bf16_t)(b.w * qscale);
        qf[dh] = f;
    }

    // staging: thread t moves ONE K slot + ONE V slot per chunk (16B each);
    // global loads amortized across the 4 waves via LDS.
    bf16x8 rK, rV;
    auto gload = [&](int it) {
        const bf16_t* g = wsh + (size_t)it * CHUNK + t * 8;
        rK = *(const bf16x8*)g;
        rV = *(const bf16x8*)(g + 2048);
    };
    auto lstore = [&](int nb) {
        *(bf16x8*)&buf[nb][t * 8]        = rK;
        *(bf16x8*)&buf[nb][2048 + t * 8] = rV;
    };

    gload(0);
    lstore(0);

    f32x4 acc[4] = {};   // [dt], C-layout: row=q(g4*4+r), col=d(c16)

    for (int it = 0; it < NIT; ++it) {
        const int cur = it & 1;
        __syncthreads();                     // buf[cur] published; prev reads done
        if (it + 1 < NIT) gload(it + 1);     // next chunk global->regs

        // K frags -> QK first (short kf live range)
        bf16x8 kf[4];
        #pragma unroll
        for (int f = 0; f < 4; ++f) kf[f] = *(const bf16x8*)&buf[cur][(f * 64 + lane) * 8];

        f32x4 s0 = {0.f, 0.f, 0.f, 0.f}, s1 = {0.f, 0.f, 0.f, 0.f};
        __builtin_amdgcn_s_setprio(1);
        s0 = __builtin_amdgcn_mfma_f32_16x16x32_bf16(kf[0], qf[0], s0, 0, 0, 0);
        s0 = __builtin_amdgcn_mfma_f32_16x16x32_bf16(kf[1], qf[1], s0, 0, 0, 0);
        s1 = __builtin_amdgcn_mfma_f32_16x16x32_bf16(kf[2], qf[0], s1, 0, 0, 0);
        s1 = __builtin_amdgcn_mfma_f32_16x16x32_bf16(kf[3], qf[1], s1, 0, 0, 0);
        __builtin_amdgcn_s_setprio(0);

        // V frag reads issued here: ds latency hides under the sigmoid
        bf16x8 vf[4];
        #pragma unroll
        for (int f = 0; f < 4; ++f) vf[f] = *(const bf16x8*)&buf[cur][2048 + (f * 64 + lane) * 8];

        // sigmoid -> bf16x8 = A-frag of 16x16x32 PV; A k-slot g4*8+j holds
        // key kappa(g4,j), matching the ws V permutation.
        bf16x8 p8;
        #pragma unroll
        for (int r = 0; r < 4; ++r) p8[r]     = (bf16_t)FAST_RCP(1.0f + FAST_EXP2(s0[r]));
        #pragma unroll
        for (int r = 0; r < 4; ++r) p8[4 + r] = (bf16_t)FAST_RCP(1.0f + FAST_EXP2(s1[r]));

        __builtin_amdgcn_s_setprio(1);
        #pragma unroll
        for (int dt = 0; dt < 4; ++dt)
            acc[dt] = __builtin_amdgcn_mfma_f32_16x16x32_bf16(p8, vf[dt], acc[dt], 0, 0, 0);
        __builtin_amdgcn_s_setprio(0);

        if (it + 1 < NIT) lstore(cur ^ 1);   // publish next chunk
    }

    const int q0 = qwave + g4 * 4;
    #pragma unroll
    for (int r = 0; r < 4; ++r) {
        float* po = Op + (size_t)(q0 + r) * DH + c16;
        po[0]  = acc[0][r];
        po[16] = acc[1][r];
        po[32] = acc[2][r];
        po[48] = acc[3][r];
    }
}

// ---------------- fallback: R7 fused single kernel (no ws needed) --------
__global__ __launch_bounds__(256, 4)
void sigattn_fallback(const float* __restrict__ Qg, const float* __restrict__ Kg,
                      const float* __restrict__ Vg, float* __restrict__ Og)
{
    static constexpr int FQPB = 128;
    __shared__ __align__(16) bf16_t buf[2][2 * CHUNK];
    const int t = threadIdx.x, wave = t >> 6, lane = t & 63;
    const int c16 = lane & 15, g4 = lane >> 4;
    const int bh = blockIdx.x, qtile = blockIdx.y;
    const size_t hbase = (size_t)bh * SEQ * DH;
    const float* Qp = Qg + hbase; const float* Kp = Kg + hbase;
    const float* Vp = Vg + hbase; float* Op = Og + hbase;
    const int qwave = qtile * FQPB + wave * 32;
    const float qscale = -0.125f * 1.44269504088896340736f;
    bf16x8 qf[2][2];
    #pragma unroll
    for (int qs = 0; qs < 2; ++qs)
        #pragma unroll
        for (int dh = 0; dh < 2; ++dh) {
            const float* p = Qp + (size_t)(qwave + qs * 16 + c16) * DH + dh * 32 + g4 * 8;
            f32x4 a = *(const f32x4*)p; f32x4 b = *(const f32x4*)(p + 4);
            bf16x8 f;
            f[0]=(bf16_t)(a.x*qscale); f[1]=(bf16_t)(a.y*qscale); f[2]=(bf16_t)(a.z*qscale); f[3]=(bf16_t)(a.w*qscale);
            f[4]=(bf16_t)(b.x*qscale); f[5]=(bf16_t)(b.y*qscale); f[6]=(bf16_t)(b.z*qscale); f[7]=(bf16_t)(b.w*qscale);
            qf[qs][dh] = f;
        }
    f32x4 kst[2][2]; float vst[2][8];
    auto issue_loads2 = [&](int su) {
        #pragma unroll
        for (int c = 0; c < 2; ++c) {
            const int kb0 = (2 * su + c) * KB;
            const float* pk = Kp + (size_t)(kb0 + (wave >> 1) * 16 + c16) * DH + (wave & 1) * 32 + g4 * 8;
            kst[c][0] = *(const f32x4*)pk; kst[c][1] = *(const f32x4*)(pk + 4);
            const float* pv = Vp + (size_t)(kb0 + g4 * 4) * DH + wave * 16 + c16;
            #pragma unroll
            for (int h = 0; h < 2; ++h)
                #pragma unroll
                for (int j = 0; j < 4; ++j) vst[c][h * 4 + j] = pv[(size_t)(h * 16 + j) * DH];
        }
    };
    auto store2 = [&](int nb) {
        #pragma unroll
        for (int c = 0; c < 2; ++c) {
            bf16x8 k8;
            #pragma unroll
            for (int i = 0; i < 4; ++i) { k8[i] = (bf16_t)kst[c][0][i]; k8[4+i] = (bf16_t)kst[c][1][i]; }
            *(bf16x8*)&buf[nb][c * CHUNK + t * 8] = k8;
            bf16x8 v8;
            #pragma unroll
            for (int j = 0; j < 8; ++j) v8[j] = (bf16_t)vst[c][j];
            *(bf16x8*)&buf[nb][c * CHUNK + 2048 + t * 8] = v8;
        }
    };
    issue_loads2(0); store2(0);
    f32x4 acc[2][4] = {};
    for (int su = 0; su < NIT / 2; ++su) {
        const int cur = su & 1;
        __syncthreads();
        if (su + 1 < NIT / 2) issue_loads2(su + 1);
        #pragma unroll
        for (int h = 0; h < 2; ++h) {
            const bf16_t* base = &buf[cur][h * CHUNK];
            bf16x8 kf[4], vf[4];
            #pragma unroll
            for (int f = 0; f < 4; ++f) kf[f] = *(const bf16x8*)&base[(f * 64 + lane) * 8];
            #pragma unroll
            for (int f = 0; f < 4; ++f) vf[f] = *(const bf16x8*)&base[2048 + (f * 64 + lane) * 8];
            #pragma unroll
            for (int qs = 0; qs < 2; ++qs) {
                f32x4 s0 = {0.f,0.f,0.f,0.f}, s1 = {0.f,0.f,0.f,0.f};
                s0 = __builtin_amdgcn_mfma_f32_16x16x32_bf16(kf[0], qf[qs][0], s0, 0, 0, 0);
                s0 = __builtin_amdgcn_mfma_f32_16x16x32_bf16(kf[1], qf[qs][1], s0, 0, 0, 0);
                s1 = __builtin_amdgcn_mfma_f32_16x16x32_bf16(kf[2], qf[qs][0], s1, 0, 0, 0);
                s1 = __builtin_amdgcn_mfma_f32_16x16x32_bf16(kf[3], qf[qs][1], s1, 0, 0, 0);
                bf16x8 p8;
                #pragma unroll
                for (int r = 0; r < 4; ++r) p8[r]     = (bf16_t)FAST_RCP(1.0f + FAST_EXP2(s0[r]));
                #pragma unroll
                for (int r = 0; r < 4; ++r) p8[4 + r] = (bf16_t)FAST_RCP(1.0f + FAST_EXP2(s1[r]));
                #pragma unroll
                for (int dt = 0; dt < 4; ++dt)
                    acc[qs][dt] = __builtin_amdgcn_mfma_f32_16x16x32_bf16(p8, vf[dt], acc[qs][dt], 0, 0, 0);
            }
        }
        if (su + 1 < NIT / 2) store2(cur ^ 1);
    }
    #pragma unroll
    for (int qs = 0; qs < 2; ++qs) {
        const int q0 = qwave + qs * 16 + g4 * 4;
        #pragma unroll
        for (int r = 0; r < 4; ++r) {
            float* po = Op + (size_t)(q0 + r) * DH + c16;
            po[0]  = acc[qs][0][r];
            po[16] = acc[qs][1][r];
            po[32] = acc[qs][2][r];
            po[48] = acc[qs][3][r];
        }
    }
}

extern "C" void kernel_launch(void* const* d_in, const int* in_sizes, int n_in,
                              void* d_out, int out_size, void* d_ws, size_t ws_size,
                              hipStream_t stream)
{
    const float* q = (const float*)d_in[0];
    const float* k = (const float*)d_in[1];
    const float* v = (const float*)d_in[2];
    float* o = (float*)d_out;
    const size_t need = 64ull * NIT * CHUNK * sizeof(bf16_t);   // 32 MB
    if (ws_size >= need) {
        sigattn_prepass<<<dim3(64, NIT), dim3(256), 0, stream>>>(k, v, (bf16_t*)d_ws);
        // grid x = bh: XCD = (x + 64*y) % 8 = bh % 8 -> per-XCD ws working
        // set = 8 heads x 512KB = 4MB, L2-resident. 2048 blocks = 8/CU.
        sigattn_main<<<dim3(64, SEQ / QPB), dim3(256), 0, stream>>>(q, (const bf16_t*)d_ws, o);
    } else {
        sigattn_fallback<<<dim3(64, SEQ / 128), dim3(256), 0, stream>>>(q, k, v, o);
    }
}

// Round 10
// 210.687 us; speedup vs baseline: 1.3162x; 1.0343x over previous
//
#include <hip/hip_runtime.h>

// Sigmoid-attention: O = sigmoid(Q K^T / 8) V per (b,h). B*H=64, S=2048, D=64.
// R13 (resubmit; R9 bench was an infra failure — container died, no data).
// Software-pipelined, issue-order-aware main (on R10's LDS-free base).
// Evidence: R6/R10/R12 all ~97-103us across {LDS+barriers, no-LDS, 2x
// occupancy} with frozen MfmaUtil~30/VALU~52 -> not latency- or staging-
// bound; waves issue IN ORDER and the serial QK->sigmoid->PV body leaves
// ~45% of cycles with nothing issuable. Fix: per iter issue a 16-MFMA
// cluster (QK(it) + PV(it-1), mutually independent), then the 8 L2 prefetch
// loads, then sigmoid(it) whose VALU/trans issue overlaps MFMA execution
// and load latency. P ping-pongs via named SSA values (no indexed arrays).
// No LDS, no barriers. Prepass unchanged (R6). Fallback = R7 fused.

typedef __bf16 bf16_t;
typedef __attribute__((ext_vector_type(8))) __bf16 bf16x8;
typedef __attribute__((ext_vector_type(4))) float  f32x4;

#if defined(__HIP_DEVICE_COMPILE__) && __has_builtin(__builtin_amdgcn_exp2f)
#define FAST_EXP2(x) __builtin_amdgcn_exp2f(x)
#else
#define FAST_EXP2(x) exp2f(x)
#endif
#if defined(__HIP_DEVICE_COMPILE__) && __has_builtin(__builtin_amdgcn_rcpf)
#define FAST_RCP(x) __builtin_amdgcn_rcpf(x)
#else
#define FAST_RCP(x) (1.0f/(x))
#endif

static constexpr int SEQ = 2048;
static constexpr int DH  = 64;
static constexpr int KB  = 32;           // keys per chunk
static constexpr int NIT = SEQ / KB;     // 64 chunks
static constexpr int QPW = 32;           // q-rows per wave
static constexpr int QPB = 128;          // q-rows per block (4 waves x 32)
static constexpr int CHUNK = 4096;       // bf16 per (head,chunk) ws block (8 KB)

// ws image layout per (head,chunk) — identical to R5/R6:
//   [0,2048)   K frags: slot(f=ks*2+dh, lane, j) =
//              K[kb + ks*16 + (lane&15)][dh*32 + (lane>>4)*8 + j]
//   [2048,4096) V frags (kappa-permuted): slot(dt, lane, j) =
//              V[kb + kappa(lane>>4,j)][dt*16 + (lane&15)],
//              kappa(g4,j) = (j>>2)*16 + g4*4 + (j&3)

// ---------------- prepass (unchanged from R6, ~20us) ---------------------
__global__ __launch_bounds__(256)
void sigattn_prepass(const float* __restrict__ Kg, const float* __restrict__ Vg,
                     bf16_t* __restrict__ ws)
{
    const int bh = blockIdx.x, it = blockIdx.y;
    const int t  = threadIdx.x;
    const int kb = it * KB;
    const size_t hbase = (size_t)bh * SEQ * DH;
    bf16_t* wbase = ws + ((size_t)bh * NIT + it) * CHUNK;

    {
        const int f = t >> 6, lane = t & 63;
        const int ks = f >> 1, dh = f & 1, c16 = lane & 15, g4 = lane >> 4;
        const float* p = Kg + hbase + (size_t)(kb + ks * 16 + c16) * DH + dh * 32 + g4 * 8;
        f32x4 a = *(const f32x4*)p;
        f32x4 b = *(const f32x4*)(p + 4);
        bf16x8 o;
        o[0] = (bf16_t)a.x; o[1] = (bf16_t)a.y; o[2] = (bf16_t)a.z; o[3] = (bf16_t)a.w;
        o[4] = (bf16_t)b.x; o[5] = (bf16_t)b.y; o[6] = (bf16_t)b.z; o[7] = (bf16_t)b.w;
        *(bf16x8*)&wbase[(size_t)t * 8] = o;
    }
    {
        const int lane = t & 63, dt = t >> 6;
        const int c16 = lane & 15, g4 = lane >> 4;
        const float* p = Vg + hbase + (size_t)kb * DH + dt * 16 + c16;
        bf16x8 o;
        #pragma unroll
        for (int j = 0; j < 8; ++j) {
            const int row = (j >> 2) * 16 + g4 * 4 + (j & 3);   // kappa(g4, j)
            o[j] = (bf16_t)p[(size_t)row * DH];
        }
        *(bf16x8*)&wbase[2048 + (size_t)t * 8] = o;
    }
}

// ---------------- main: LDS-free, software-pipelined ---------------------
__global__ __launch_bounds__(256, 4)
void sigattn_main(const float* __restrict__ Qg, const bf16_t* __restrict__ ws,
                  float* __restrict__ Og)
{
    const int t    = threadIdx.x;
    const int wave = t >> 6;
    const int lane = t & 63;
    const int c16  = lane & 15;
    const int g4   = lane >> 4;

    const int bh    = blockIdx.x;
    const int qtile = blockIdx.y;

    const float* Qp = Qg + (size_t)bh * SEQ * DH;
    float*       Op = Og + (size_t)bh * SEQ * DH;
    const bf16_t* wsh = ws + (size_t)bh * NIT * CHUNK;

    const int qwave = qtile * QPB + wave * QPW;

    // Q fragments (pre-scaled by -log2(e)/8): B-frag layout
    const float qscale = -0.125f * 1.44269504088896340736f;
    bf16x8 qf[2][2];
    #pragma unroll
    for (int qs = 0; qs < 2; ++qs) {
        #pragma unroll
        for (int dh = 0; dh < 2; ++dh) {
            const float* p = Qp + (size_t)(qwave + qs * 16 + c16) * DH + dh * 32 + g4 * 8;
            f32x4 a = *(const f32x4*)p;
            f32x4 b = *(const f32x4*)(p + 4);
            bf16x8 f;
            f[0] = (bf16_t)(a.x * qscale); f[1] = (bf16_t)(a.y * qscale);
            f[2] = (bf16_t)(a.z * qscale); f[3] = (bf16_t)(a.w * qscale);
            f[4] = (bf16_t)(b.x * qscale); f[5] = (bf16_t)(b.y * qscale);
            f[6] = (bf16_t)(b.z * qscale); f[7] = (bf16_t)(b.w * qscale);
            qf[qs][dh] = f;
        }
    }

    // per-lane base into the frag image: slot (f*64+lane) -> byte-linear
    const bf16_t* lbase = wsh + (size_t)lane * 8;
    auto kaddr = [&](int it, int f) {
        return (const bf16x8*)&lbase[(size_t)it * CHUNK + f * 512];
    };
    auto vaddr = [&](int it, int f) {
        return (const bf16x8*)&lbase[(size_t)it * CHUNK + 2048 + f * 512];
    };

    // sigmoid of 8 scores -> PV A-fragment (bf16x8)
    auto sig8 = [&](const f32x4& s0, const f32x4& s1) -> bf16x8 {
        bf16x8 p;
        #pragma unroll
        for (int r = 0; r < 4; ++r) p[r]     = (bf16_t)FAST_RCP(1.0f + FAST_EXP2(s0[r]));
        #pragma unroll
        for (int r = 0; r < 4; ++r) p[4 + r] = (bf16_t)FAST_RCP(1.0f + FAST_EXP2(s1[r]));
        return p;
    };

    f32x4 acc[2][4] = {};   // [qs][dt], C-layout: row=q(g4*4+r), col=d(c16)

    bf16x8 kf[4], vf[4];
    bf16x8 pA0, pA1;        // P(it-1) ping-pong state (SSA values, no arrays)

    // ---- prolog: it = 0 ----
    #pragma unroll
    for (int f = 0; f < 4; ++f) kf[f] = *kaddr(0, f);
    {
        f32x4 s0a = {0,0,0,0}, s1a = {0,0,0,0}, s0b = {0,0,0,0}, s1b = {0,0,0,0};
        __builtin_amdgcn_s_setprio(1);
        s0a = __builtin_amdgcn_mfma_f32_16x16x32_bf16(kf[0], qf[0][0], s0a, 0, 0, 0);
        s0a = __builtin_amdgcn_mfma_f32_16x16x32_bf16(kf[1], qf[0][1], s0a, 0, 0, 0);
        s1a = __builtin_amdgcn_mfma_f32_16x16x32_bf16(kf[2], qf[0][0], s1a, 0, 0, 0);
        s1a = __builtin_amdgcn_mfma_f32_16x16x32_bf16(kf[3], qf[0][1], s1a, 0, 0, 0);
        s0b = __builtin_amdgcn_mfma_f32_16x16x32_bf16(kf[0], qf[1][0], s0b, 0, 0, 0);
        s0b = __builtin_amdgcn_mfma_f32_16x16x32_bf16(kf[1], qf[1][1], s0b, 0, 0, 0);
        s1b = __builtin_amdgcn_mfma_f32_16x16x32_bf16(kf[2], qf[1][0], s1b, 0, 0, 0);
        s1b = __builtin_amdgcn_mfma_f32_16x16x32_bf16(kf[3], qf[1][1], s1b, 0, 0, 0);
        __builtin_amdgcn_s_setprio(0);
        // prefetch K(1) (kf free after QK issue; HW scoreboards WAR)
        #pragma unroll
        for (int f = 0; f < 4; ++f) kf[f] = *kaddr(1, f);
        // sigmoid(0) overlaps the prefetch + MFMA drain
        pA0 = sig8(s0a, s1a);
        pA1 = sig8(s0b, s1b);
        // prefetch V(0) for the first PV (consumed next iter's cluster)
        #pragma unroll
        for (int f = 0; f < 4; ++f) vf[f] = *vaddr(0, f);
    }

    // ---- steady state: it = 1 .. NIT-1 ----
    for (int it = 1; it < NIT; ++it) {
        // 16-MFMA cluster: QK(it) + PV(it-1) — mutually independent
        f32x4 s0a = {0,0,0,0}, s1a = {0,0,0,0}, s0b = {0,0,0,0}, s1b = {0,0,0,0};
        __builtin_amdgcn_s_setprio(1);
        s0a = __builtin_amdgcn_mfma_f32_16x16x32_bf16(kf[0], qf[0][0], s0a, 0, 0, 0);
        s0a = __builtin_amdgcn_mfma_f32_16x16x32_bf16(kf[1], qf[0][1], s0a, 0, 0, 0);
        s1a = __builtin_amdgcn_mfma_f32_16x16x32_bf16(kf[2], qf[0][0], s1a, 0, 0, 0);
        s1a = __builtin_amdgcn_mfma_f32_16x16x32_bf16(kf[3], qf[0][1], s1a, 0, 0, 0);
        s0b = __builtin_amdgcn_mfma_f32_16x16x32_bf16(kf[0], qf[1][0], s0b, 0, 0, 0);
        s0b = __builtin_amdgcn_mfma_f32_16x16x32_bf16(kf[1], qf[1][1], s0b, 0, 0, 0);
        s1b = __builtin_amdgcn_mfma_f32_16x16x32_bf16(kf[2], qf[1][0], s1b, 0, 0, 0);
        s1b = __builtin_amdgcn_mfma_f32_16x16x32_bf16(kf[3], qf[1][1], s1b, 0, 0, 0);
        #pragma unroll
        for (int dt = 0; dt < 4; ++dt)
            acc[0][dt] = __builtin_amdgcn_mfma_f32_16x16x32_bf16(pA0, vf[dt], acc[0][dt], 0, 0, 0);
        #pragma unroll
        for (int dt = 0; dt < 4; ++dt)
            acc[1][dt] = __builtin_amdgcn_mfma_f32_16x16x32_bf16(pA1, vf[dt], acc[1][dt], 0, 0, 0);
        __builtin_amdgcn_s_setprio(0);

        // prefetch K(it+1) (clamped: last iter re-reads NIT-1, harmless)
        const int itn = (it + 1 < NIT) ? it + 1 : NIT - 1;
        #pragma unroll
        for (int f = 0; f < 4; ++f) kf[f] = *kaddr(itn, f);
        // prefetch V(it) (vf freed by PV(it-1) above; consumed next cluster)
        #pragma unroll
        for (int f = 0; f < 4; ++f) vf[f] = *vaddr(it, f);

        // sigmoid(it): VALU/trans issue overlaps MFMA execution + L2 latency
        bf16x8 pn0 = sig8(s0a, s1a);
        bf16x8 pn1 = sig8(s0b, s1b);
        pA0 = pn0;
        pA1 = pn1;
    }

    // ---- epilog: PV(NIT-1) ----
    __builtin_amdgcn_s_setprio(1);
    #pragma unroll
    for (int dt = 0; dt < 4; ++dt)
        acc[0][dt] = __builtin_amdgcn_mfma_f32_16x16x32_bf16(pA0, vf[dt], acc[0][dt], 0, 0, 0);
    #pragma unroll
    for (int dt = 0; dt < 4; ++dt)
        acc[1][dt] = __builtin_amdgcn_mfma_f32_16x16x32_bf16(pA1, vf[dt], acc[1][dt], 0, 0, 0);
    __builtin_amdgcn_s_setprio(0);

    #pragma unroll
    for (int qs = 0; qs < 2; ++qs) {
        const int q0 = qwave + qs * 16 + g4 * 4;
        #pragma unroll
        for (int r = 0; r < 4; ++r) {
            float* po = Op + (size_t)(q0 + r) * DH + c16;
            po[0]  = acc[qs][0][r];
            po[16] = acc[qs][1][r];
            po[32] = acc[qs][2][r];
            po[48] = acc[qs][3][r];
        }
    }
}

// ---------------- fallback: R7 fused single kernel (no ws needed) --------
__global__ __launch_bounds__(256, 4)
void sigattn_fallback(const float* __restrict__ Qg, const float* __restrict__ Kg,
                      const float* __restrict__ Vg, float* __restrict__ Og)
{
    static constexpr int FQPB = 128;
    __shared__ __align__(16) bf16_t buf[2][2 * CHUNK];
    const int t = threadIdx.x, wave = t >> 6, lane = t & 63;
    const int c16 = lane & 15, g4 = lane >> 4;
    const int bh = blockIdx.x, qtile = blockIdx.y;
    const size_t hbase = (size_t)bh * SEQ * DH;
    const float* Qp = Qg + hbase; const float* Kp = Kg + hbase;
    const float* Vp = Vg + hbase; float* Op = Og + hbase;
    const int qwave = qtile * FQPB + wave * 32;
    const float qscale = -0.125f * 1.44269504088896340736f;
    bf16x8 qf[2][2];
    #pragma unroll
    for (int qs = 0; qs < 2; ++qs)
        #pragma unroll
        for (int dh = 0; dh < 2; ++dh) {
            const float* p = Qp + (size_t)(qwave + qs * 16 + c16) * DH + dh * 32 + g4 * 8;
            f32x4 a = *(const f32x4*)p; f32x4 b = *(const f32x4*)(p + 4);
            bf16x8 f;
            f[0]=(bf16_t)(a.x*qscale); f[1]=(bf16_t)(a.y*qscale); f[2]=(bf16_t)(a.z*qscale); f[3]=(bf16_t)(a.w*qscale);
            f[4]=(bf16_t)(b.x*qscale); f[5]=(bf16_t)(b.y*qscale); f[6]=(bf16_t)(b.z*qscale); f[7]=(bf16_t)(b.w*qscale);
            qf[qs][dh] = f;
        }
    f32x4 kst[2][2]; float vst[2][8];
    auto issue_loads2 = [&](int su) {
        #pragma unroll
        for (int c = 0; c < 2; ++c) {
            const int kb0 = (2 * su + c) * KB;
            const float* pk = Kp + (size_t)(kb0 + (wave >> 1) * 16 + c16) * DH + (wave & 1) * 32 + g4 * 8;
            kst[c][0] = *(const f32x4*)pk; kst[c][1] = *(const f32x4*)(pk + 4);
            const float* pv = Vp + (size_t)(kb0 + g4 * 4) * DH + wave * 16 + c16;
            #pragma unroll
            for (int h = 0; h < 2; ++h)
                #pragma unroll
                for (int j = 0; j < 4; ++j) vst[c][h * 4 + j] = pv[(size_t)(h * 16 + j) * DH];
        }
    };
    auto store2 = [&](int nb) {
        #pragma unroll
        for (int c = 0; c < 2; ++c) {
            bf16x8 k8;
            #pragma unroll
            for (int i = 0; i < 4; ++i) { k8[i] = (bf16_t)kst[c][0][i]; k8[4+i] = (bf16_t)kst[c][1][i]; }
            *(bf16x8*)&buf[nb][c * CHUNK + t * 8] = k8;
            bf16x8 v8;
            #pragma unroll
            for (int j = 0; j < 8; ++j) v8[j] = (bf16_t)vst[c][j];
            *(bf16x8*)&buf[nb][c * CHUNK + 2048 + t * 8] = v8;
        }
    };
    issue_loads2(0); store2(0);
    f32x4 acc[2][4] = {};
    for (int su = 0; su < NIT / 2; ++su) {
        const int cur = su & 1;
        __syncthreads();
        if (su + 1 < NIT / 2) issue_loads2(su + 1);
        #pragma unroll
        for (int h = 0; h < 2; ++h) {
            const bf16_t* base = &buf[cur][h * CHUNK];
            bf16x8 kf[4], vf[4];
            #pragma unroll
            for (int f = 0; f < 4; ++f) kf[f] = *(const bf16x8*)&base[(f * 64 + lane) * 8];
            #pragma unroll
            for (int f = 0; f < 4; ++f) vf[f] = *(const bf16x8*)&base[2048 + (f * 64 + lane) * 8];
            #pragma unroll
            for (int qs = 0; qs < 2; ++qs) {
                f32x4 s0 = {0.f,0.f,0.f,0.f}, s1 = {0.f,0.f,0.f,0.f};
                s0 = __builtin_amdgcn_mfma_f32_16x16x32_bf16(kf[0], qf[qs][0], s0, 0, 0, 0);
                s0 = __builtin_amdgcn_mfma_f32_16x16x32_bf16(kf[1], qf[qs][1], s0, 0, 0, 0);
                s1 = __builtin_amdgcn_mfma_f32_16x16x32_bf16(kf[2], qf[qs][0], s1, 0, 0, 0);
                s1 = __builtin_amdgcn_mfma_f32_16x16x32_bf16(kf[3], qf[qs][1], s1, 0, 0, 0);
                bf16x8 p8;
                #pragma unroll
                for (int r = 0; r < 4; ++r) p8[r]     = (bf16_t)FAST_RCP(1.0f + FAST_EXP2(s0[r]));
                #pragma unroll
                for (int r = 0; r < 4; ++r) p8[4 + r] = (bf16_t)FAST_RCP(1.0f + FAST_EXP2(s1[r]));
                #pragma unroll
                for (int dt = 0; dt < 4; ++dt)
                    acc[qs][dt] = __builtin_amdgcn_mfma_f32_16x16x32_bf16(p8, vf[dt], acc[qs][dt], 0, 0, 0);
            }
        }
        if (su + 1 < NIT / 2) store2(cur ^ 1);
    }
    #pragma unroll
    for (int qs = 0; qs < 2; ++qs) {
        const int q0 = qwave + qs * 16 + g4 * 4;
        #pragma unroll
        for (int r = 0; r < 4; ++r) {
            float* po = Op + (size_t)(q0 + r) * DH + c16;
            po[0]  = acc[qs][0][r];
            po[16] = acc[qs][1][r];
            po[32] = acc[qs][2][r];
            po[48] = acc[qs][3][r];
        }
    }
}

extern "C" void kernel_launch(void* const* d_in, const int* in_sizes, int n_in,
                              void* d_out, int out_size, void* d_ws, size_t ws_size,
                              hipStream_t stream)
{
    const float* q = (const float*)d_in[0];
    const float* k = (const float*)d_in[1];
    const float* v = (const float*)d_in[2];
    float* o = (float*)d_out;
    const size_t need = 64ull * NIT * CHUNK * sizeof(bf16_t);   // 32 MB
    if (ws_size >= need) {
        sigattn_prepass<<<dim3(64, NIT), dim3(256), 0, stream>>>(k, v, (bf16_t*)d_ws);
        // grid x = bh: XCD = bh % 8 -> per-XCD ws working set 4MB, L2-resident
        sigattn_main<<<dim3(64, SEQ / QPB), dim3(256), 0, stream>>>(q, (const bf16_t*)d_ws, o);
    } else {
        sigattn_fallback<<<dim3(64, SEQ / 128), dim3(256), 0, stream>>>(q, k, v, o);
    }
}